// Round 6
// baseline (178.929 us; speedup 1.0000x reference)
//
#include <hip/hip_runtime.h>
#include <math.h>

#define T_LEN      24000
#define W_LEN      81
#define HALF_W     40
#define NK         21
#define MAXORD     10
#define NIMG_TOTAL 1561          // |{k in [-10,10]^3 : |kx|+|ky|+|kz| <= 10}|
#define FS_F       48000.0f
#define C_F        343.0f
#define FS_OVER_C  (48000.0f / 343.0f)
#define PI_F       3.14159265358979323846f
#define FOUR_PI_F  12.566370614359172f
#define NEG_SLOPE  0.01f
#define NTHREADS   1024
#define NWAVES     16

// LDS pool layout (floats):
//   rir    : 24000                    (offset 0)
//   params : 1561 float4 = 6244      (offset 24000, 16B-aligned)
//   hann   : 84
//   dsq    : 63
//   bp     : 12
//   mlp    : sm_in 22 + h1 30 + h2 20 + zb 9 + rms 9 = 90
//   cnt    : 1 (+pad)
#define OFF_PARAMS 24000
#define OFF_HANN   (OFF_PARAMS + 4 * NIMG_TOTAL)   // 30244
#define OFF_DSQ    (OFF_HANN + 84)
#define OFF_BP     (OFF_DSQ + 63)
#define OFF_MLP    (OFF_BP + 12)
#define OFF_CNT    (OFF_MLP + 90)
#define SMEM_FLOATS (OFF_CNT + 2)
#define SMEM_BYTES  (SMEM_FLOATS * 4)              // ~122 KB (needs gfx950 160KB LDS)

// ---- compile-time table of valid image triples ----
// entry: (order << 15) | (kxi << 10) | (kyi << 5) | kzi
struct Table { unsigned int e[NIMG_TOTAL]; };

constexpr Table make_table() {
    Table t{};
    int n = 0;
    for (int kx = 0; kx < NK; ++kx)
        for (int ky = 0; ky < NK; ++ky)
            for (int kz = 0; kz < NK; ++kz) {
                int ax = kx >= MAXORD ? kx - MAXORD : MAXORD - kx;
                int ay = ky >= MAXORD ? ky - MAXORD : MAXORD - ky;
                int az = kz >= MAXORD ? kz - MAXORD : MAXORD - kz;
                int order = ax + ay + az;
                if (order <= MAXORD)
                    t.e[n++] = (unsigned)((order << 15) | (kx << 10) | (ky << 5) | kz);
            }
    return t;
}
__constant__ Table g_tbl = make_table();

__global__ __launch_bounds__(NTHREADS, 1)
void rir_row_kernel(const float* __restrict__ g_in,
                    const float* __restrict__ W1, const float* __restrict__ b1,
                    const float* __restrict__ W2, const float* __restrict__ b2,
                    const float* __restrict__ W3, const float* __restrict__ b3,
                    float* __restrict__ out_rir, float* __restrict__ out_origin)
{
    extern __shared__ float smem[];
    float*  rir    = smem;
    float4* params = (float4*)(smem + OFF_PARAMS);
    float*  hann   = smem + OFF_HANN;
    float*  dsq    = smem + OFF_DSQ;
    float*  bp     = smem + OFF_BP;
    float*  sm_in  = smem + OFF_MLP;         // 22
    float*  h1     = sm_in + 22;             // 30
    float*  h2     = h1 + 30;                // 20
    float*  zb     = h2 + 20;                // 9
    float*  rms    = zb + 9;                 // 9: room, mic, src
    int*    cnt    = (int*)(smem + OFF_CNT);

    const int tid  = threadIdx.x;
    const int lane = tid & 63;
    const int wave = tid >> 6;
    const int b    = blockIdx.x;

    // ---- zero rir (float4), small tables ----
    float4* rir4 = (float4*)rir;
    #pragma unroll
    for (int i = tid; i < T_LEN / 4; i += NTHREADS)
        rir4[i] = make_float4(0.f, 0.f, 0.f, 0.f);

    if (tid >= 128 && tid < 128 + W_LEN) {
        int j = tid - 128;
        hann[j] = 0.5f * (1.0f - cosf(2.0f * PI_F * (float)j / 80.0f));
    }
    if (tid >= 256 && tid <= 256 + MAXORD)
        bp[tid - 256] = powf(0.9f, (float)(tid - 256)) * (1.0f / FOUR_PI_F);
    if (tid == 320) *cnt = 0;

    // ---- wave 0: input row, MLP, geometry (in-wave LDS ordering) ----
    if (tid < 64) {
        if (tid < 22) sm_in[tid] = g_in[b * 22 + tid];
        if (tid < 30) {
            float a = b1[tid];
            const float* w = W1 + tid * 22;
            #pragma unroll
            for (int i = 0; i < 22; ++i) a += sm_in[i] * w[i];
            h1[tid] = (a >= 0.0f) ? a : NEG_SLOPE * a;
        }
        if (tid < 20) {
            float a = b2[tid];
            const float* w = W2 + tid * 30;
            #pragma unroll
            for (int i = 0; i < 30; ++i) a += h1[i] * w[i];
            h2[tid] = (a >= 0.0f) ? a : NEG_SLOPE * a;
        }
        if (tid < 9) {
            float a = b3[tid];
            const float* w = W3 + tid * 20;
            #pragma unroll
            for (int i = 0; i < 20; ++i) a += h2[i] * w[i];
            zb[tid] = 1.0f / (1.0f + __expf(-a));
        }
        if (tid < 3) {
            float room = zb[tid] * 20.0f;
            rms[tid]     = room;
            rms[3 + tid] = zb[3 + tid] * room;   // mic
            rms[6 + tid] = zb[6 + tid] * room;   // src
        }
        if (tid == 0) {
            float dx = rms[3] - rms[6], dy = rms[4] - rms[7], dz = rms[5] - rms[8];
            out_origin[b] = 40.0f + FS_F * sqrtf(dx * dx + dy * dy + dz * dz) / C_F;
        }
        if (tid < 3 * NK) {
            int a  = tid / NK;
            int kk = (tid - a * NK) - MAXORD;
            float L = rms[a], src = rms[6 + a];
            float img = ((kk & 1) == 0) ? (float)kk * L + src : (float)(kk + 1) * L - src;
            float diff = img - rms[3 + a];
            dsq[tid] = diff * diff;
        }
    }
    __syncthreads();

    // ---- enumerate all images ONCE; precompute per-image scatter params ----
    // Keep image iff its window start t0-40 < T (delay >= 40 guarantees t0 >= 40).
    for (int i = tid; i < NIMG_TOTAL; i += NTHREADS) {
        unsigned e = g_tbl.e[i];
        int kzi = e & 31, kyi = (e >> 5) & 31, kxi = (e >> 10) & 31, order = (int)(e >> 15);
        float d     = sqrtf(dsq[kxi] + dsq[NK + kyi] + dsq[2 * NK + kzi]);
        float delay = 40.0f + d * FS_OVER_C;
        float t0f   = floorf(delay);
        if (t0f < (float)(T_LEN + HALF_W)) {
            float frac = delay - t0f;
            float amp  = bp[order] * __builtin_amdgcn_rcpf(fmaxf(d, 0.001f));
            float sp   = __sinf(PI_F * frac);
            int pos = atomicAdd(cnt, 1);
            params[pos] = make_float4(amp, frac, sp, t0f);
        }
    }
    __syncthreads();

    // ---- scatter: image-per-wave round-robin, taps lane-parallel ----
    // Lane handles taps j0 = (lane - ws) mod 64 and j0 + 64 (j0 <= 16); consecutive
    // lanes -> consecutive LDS addresses -> conflict-free ds_add.
    const int n = *cnt;
    for (int i = wave; i < n; i += NWAVES) {
        float4 p  = params[i];                // amp, frac, sin(pi*frac), t0
        int   ws  = (int)p.w - HALF_W;        // window start (>= 0)
        int   j0  = (lane - ws) & 63;
        int   idx = ws + j0;
        int   n1  = j0 - HALF_W;
        float x1  = (float)n1 - p.y;          // t - delay
        float sg  = (n1 & 1) ? p.z : -p.z;    // sin(pi(n-frac)) = -(-1)^n sin(pi frac)
        float sv1 = (x1 == 0.0f) ? 1.0f : sg * __builtin_amdgcn_rcpf(PI_F * x1);
        if (idx < T_LEN)
            atomicAdd(&rir[idx], p.x * sv1 * hann[j0]);
        if (j0 <= W_LEN - 65) {               // second tap j = j0 + 64 (same parity)
            int   idx2 = idx + 64;
            float x2   = x1 + 64.0f;          // >= 23, never 0
            float sv2  = sg * __builtin_amdgcn_rcpf(PI_F * x2);
            if (idx2 < T_LEN)
                atomicAdd(&rir[idx2], p.x * sv2 * hann[j0 + 64]);
        }
    }
    __syncthreads();

    // ---- coalesced float4 writeback of the whole row ----
    float4* out4 = (float4*)(out_rir + (size_t)b * T_LEN);
    #pragma unroll
    for (int i = tid; i < T_LEN / 4; i += NTHREADS) out4[i] = rir4[i];
}

extern "C" void kernel_launch(void* const* d_in, const int* in_sizes, int n_in,
                              void* d_out, int out_size, void* d_ws, size_t ws_size,
                              hipStream_t stream) {
    const float* g_in = (const float*)d_in[0];
    const float* W1   = (const float*)d_in[1];
    const float* b1   = (const float*)d_in[2];
    const float* W2   = (const float*)d_in[3];
    const float* b2   = (const float*)d_in[4];
    const float* W3   = (const float*)d_in[5];
    const float* b3   = (const float*)d_in[6];

    const int B = in_sizes[0] / 22;

    float* out_rir    = (float*)d_out;
    float* out_origin = out_rir + (size_t)B * T_LEN;

    // ~122 KB dynamic LDS (gfx950 has 160 KiB/CU)
    (void)hipFuncSetAttribute((const void*)rir_row_kernel,
                              hipFuncAttributeMaxDynamicSharedMemorySize,
                              SMEM_BYTES);

    rir_row_kernel<<<B, NTHREADS, SMEM_BYTES, stream>>>(
        g_in, W1, b1, W2, b2, W3, b3, out_rir, out_origin);
}

// Round 7
// 168.889 us; speedup vs baseline: 1.0594x; 1.0594x over previous
//
#include <hip/hip_runtime.h>
#include <math.h>

#define T_LEN      24000
#define TS         3584          // samples per slice
#define NSLICE     7             // 7 * 3584 = 25088 >= 24000 (last slice: 2496 valid)
#define W_LEN      81
#define HALF_W     40
#define NK         21
#define MAXORD     10
#define NIMG_TOTAL 1561          // |{k in [-10,10]^3 : |kx|+|ky|+|kz| <= 10}|
#define FS_F       48000.0f
#define C_F        343.0f
#define FS_OVER_C  (48000.0f / 343.0f)
#define PI_F       3.14159265358979323846f
#define FOUR_PI_F  12.566370614359172f
#define NEG_SLOPE  0.01f
#define NTHREADS   512
#define NWAVES     8

// ---- compile-time table of valid image triples ----
// entry: (order << 15) | (kxi << 10) | (kyi << 5) | kzi
struct Table { unsigned int e[NIMG_TOTAL]; };

constexpr Table make_table() {
    Table t{};
    int n = 0;
    for (int kx = 0; kx < NK; ++kx)
        for (int ky = 0; ky < NK; ++ky)
            for (int kz = 0; kz < NK; ++kz) {
                int ax = kx >= MAXORD ? kx - MAXORD : MAXORD - kx;
                int ay = ky >= MAXORD ? ky - MAXORD : MAXORD - ky;
                int az = kz >= MAXORD ? kz - MAXORD : MAXORD - kz;
                int order = ax + ay + az;
                if (order <= MAXORD)
                    t.e[n++] = (unsigned)((order << 15) | (kx << 10) | (ky << 5) | kz);
            }
    return t;
}
__constant__ Table g_tbl = make_table();

// LDS ~28 KB total -> 4 blocks/CU (32 waves/CU = 8 waves/SIMD, the max)
__global__ __launch_bounds__(NTHREADS, 8)
void rir_slice8_kernel(const float* __restrict__ g_in,
                       const float* __restrict__ W1, const float* __restrict__ b1,
                       const float* __restrict__ W2, const float* __restrict__ b2,
                       const float* __restrict__ W3, const float* __restrict__ b3,
                       float* __restrict__ out_rir, float* __restrict__ out_origin)
{
    __shared__ __align__(16) float rir[TS];          // 14336 B
    __shared__ float2 params[NIMG_TOTAL + 7];        // 12544 B (amp, delay)
    __shared__ float hann[W_LEN];
    __shared__ float dsq[3 * NK];                    // (img - mic)^2 per axis
    __shared__ float bp[MAXORD + 1];                 // 0.9^o / (4*pi)
    __shared__ float h1[30], h2[20], zb[9], sm_in[22], rms[9];
    __shared__ int cnt;

    const int tid  = threadIdx.x;
    const int lane = tid & 63;
    const int wave = tid >> 6;
    const int s    = blockIdx.x;         // time slice
    const int b    = blockIdx.y;         // batch row
    const int lo   = s * TS;
    const int nout = min(TS, T_LEN - lo);   // 3584, or 2496 for last slice

    // ---- zero the slice accumulator (float4) ----
    float4* rir4 = (float4*)rir;
    #pragma unroll
    for (int i = tid; i < TS / 4; i += NTHREADS)
        rir4[i] = make_float4(0.f, 0.f, 0.f, 0.f);

    // ---- small tables (waves 2-5), counter ----
    if (tid >= 128 && tid < 128 + W_LEN) {
        int j = tid - 128;
        hann[j] = 0.5f * (1.0f - cosf(2.0f * PI_F * (float)j / 80.0f));
    }
    if (tid >= 256 && tid <= 256 + MAXORD)
        bp[tid - 256] = powf(0.9f, (float)(tid - 256)) * (1.0f / FOUR_PI_F);
    if (tid == 320) cnt = 0;

    // ---- wave 0: input row, MLP, geometry (in-wave LDS ordering) ----
    if (tid < 64) {
        if (tid < 22) sm_in[tid] = g_in[b * 22 + tid];
        if (tid < 30) {
            float a = b1[tid];
            const float* w = W1 + tid * 22;
            #pragma unroll
            for (int i = 0; i < 22; ++i) a += sm_in[i] * w[i];
            h1[tid] = (a >= 0.0f) ? a : NEG_SLOPE * a;
        }
        if (tid < 20) {
            float a = b2[tid];
            const float* w = W2 + tid * 30;
            #pragma unroll
            for (int i = 0; i < 30; ++i) a += h1[i] * w[i];
            h2[tid] = (a >= 0.0f) ? a : NEG_SLOPE * a;
        }
        if (tid < 9) {
            float a = b3[tid];
            const float* w = W3 + tid * 20;
            #pragma unroll
            for (int i = 0; i < 20; ++i) a += h2[i] * w[i];
            zb[tid] = 1.0f / (1.0f + __expf(-a));
        }
        if (tid < 3) {
            float room = zb[tid] * 20.0f;
            rms[tid]     = room;
            rms[3 + tid] = zb[3 + tid] * room;   // mic
            rms[6 + tid] = zb[6 + tid] * room;   // src
        }
        if (tid == 0 && s == 0) {
            float dx = rms[3] - rms[6], dy = rms[4] - rms[7], dz = rms[5] - rms[8];
            out_origin[b] = 40.0f + FS_F * sqrtf(dx * dx + dy * dy + dz * dz) / C_F;
        }
        if (tid < 3 * NK) {
            int a  = tid / NK;
            int kk = (tid - a * NK) - MAXORD;
            float L = rms[a], src = rms[6 + a];
            float img = ((kk & 1) == 0) ? (float)kk * L + src : (float)(kk + 1) * L - src;
            float diff = img - rms[3 + a];
            dsq[tid] = diff * diff;
        }
    }
    __syncthreads();

    // ---- enumerate valid images whose window touches this slice ----
    // keep iff t0 in [lo-40, lo+nout+39]  (t0 integer-valued)
    const float lof = (float)lo - 40.5f;
    const float hif = (float)(lo + nout) + 39.5f;
    for (int i = tid; i < NIMG_TOTAL; i += NTHREADS) {
        unsigned e = g_tbl.e[i];
        int kzi = e & 31, kyi = (e >> 5) & 31, kxi = (e >> 10) & 31, order = (int)(e >> 15);
        float d     = sqrtf(dsq[kxi] + dsq[NK + kyi] + dsq[2 * NK + kzi]);
        float delay = 40.0f + d * FS_OVER_C;
        float t0f   = floorf(delay);
        if (t0f > lof && t0f < hif) {
            float amp = bp[order] * __builtin_amdgcn_rcpf(fmaxf(d, 0.001f));
            int pos = atomicAdd(&cnt, 1);
            params[pos] = make_float2(amp, delay);
        }
    }
    __syncthreads();

    // ---- scatter: images round-robin over 8 waves, taps lane-parallel ----
    // Lane handles taps j0 = (lane - ws) mod 64 and j0 + 64 (j0 <= 16);
    // consecutive lanes -> consecutive LDS addresses -> conflict-free ds_add,
    // no intra-wave same-address collisions.
    const int n = cnt;
    for (int i = wave; i < n; i += NWAVES) {
        float2 p   = params[i];               // uniform-address broadcast read
        float t0f  = floorf(p.y);
        float frac = p.y - t0f;
        float sp   = __sinf(PI_F * frac);
        int   ws   = (int)t0f - HALF_W;       // window start (global sample)
        int   j0   = (lane - ws) & 63;
        int   idx  = ws + j0 - lo;            // local sample of tap j0
        int   n1   = j0 - HALF_W;
        float x1   = (float)n1 - frac;        // t - delay
        float sg   = (n1 & 1) ? sp : -sp;     // sin(pi(n-frac)) = -(-1)^n sin(pi frac)
        float sv1  = (x1 == 0.0f) ? 1.0f : sg * __builtin_amdgcn_rcpf(PI_F * x1);
        if ((unsigned)idx < (unsigned)nout)
            atomicAdd(&rir[idx], p.x * sv1 * hann[j0]);
        if (j0 <= W_LEN - 65) {               // second tap j = j0 + 64 (same parity)
            int   idx2 = idx + 64;
            float x2   = x1 + 64.0f;          // in [23, 88), never 0
            float sv2  = sg * __builtin_amdgcn_rcpf(PI_F * x2);
            if ((unsigned)idx2 < (unsigned)nout)
                atomicAdd(&rir[idx2], p.x * sv2 * hann[j0 + 64]);
        }
    }
    __syncthreads();

    // ---- coalesced float4 writeback of this slice ----
    float4* out4 = (float4*)(out_rir + (size_t)b * T_LEN + lo);
    for (int i = tid; i < nout / 4; i += NTHREADS) out4[i] = rir4[i];
}

extern "C" void kernel_launch(void* const* d_in, const int* in_sizes, int n_in,
                              void* d_out, int out_size, void* d_ws, size_t ws_size,
                              hipStream_t stream) {
    const float* g_in = (const float*)d_in[0];
    const float* W1   = (const float*)d_in[1];
    const float* b1   = (const float*)d_in[2];
    const float* W2   = (const float*)d_in[3];
    const float* b2   = (const float*)d_in[4];
    const float* W3   = (const float*)d_in[5];
    const float* b3   = (const float*)d_in[6];

    const int B = in_sizes[0] / 22;

    float* out_rir    = (float*)d_out;
    float* out_origin = out_rir + (size_t)B * T_LEN;

    dim3 grid(NSLICE, B);
    rir_slice8_kernel<<<grid, NTHREADS, 0, stream>>>(
        g_in, W1, b1, W2, b2, W3, b3, out_rir, out_origin);
}